// Round 5
// baseline (1747.884 us; speedup 1.0000x reference)
//
#include <hip/hip_runtime.h>
#include <cstddef>

// DecoderLayer: T=4, B=4, N=512, D=512, F=2048, H=8, head_dim=64
// I/O: float32. Spike intermediates: bf16 (exact for {0,1,2}).
// f64 MFMA GEMMs (matches np float64 ref; rounds 3/4 proved absmax 0.0).
// Round 5: 128x64 block tile (32 bn x 4 t rows), wave tile 64x32 ->
// 8 MFMA per kc vs 6 LDS reads; 4x MFMA work per barrier pair.
#define T_STEPS 4
#define BN 2048                    /* B*N rows per time plane */
#define N_TOK 512
#define D_DIM 512
#define F_DIM 2048

#define MODE_SPK 0
#define MODE_SPK_ADD 1
#define MODE_OUT 2

typedef double d4 __attribute__((ext_vector_type(4)));

__device__ __forceinline__ float bf2f(unsigned short u) {
  unsigned int x = ((unsigned int)u) << 16;
  float f;
  __builtin_memcpy(&f, &x, 4);
  return f;
}
__device__ __forceinline__ unsigned short f2bf(float f) {
  unsigned int x;
  __builtin_memcpy(&x, &f, 4);
  x += 0x7fffu + ((x >> 16) & 1u);  // round to nearest even
  return (unsigned short)(x >> 16);
}

// ---------------------------------------------------------------------------
// MFMA-f64 fused GEMM + LIF over T.
// Block tile: 128 rows x 64 cols; tile-row r = t*32 + bn_local.
// 4 waves: wr=wave>>1 (row half, 64 rows), wc=wave&1 (col half, 32 cols).
// Wave tile 64x32 = 4 m-tiles (mt) x 2 n-tiles (nt) of 16x16, f64 mfma K=4.
// mt0: (t=2wr, bn g0) mt1: (t=2wr, g1) mt2: (t=2wr+1, g0) mt3: (t=2wr+1, g1)
// C/D 16x16 layout: col=lane&15, row=(lane>>4)*4+j  (verified round 4).
// Waves wr=1 (t=2,3) ship accs via LDS; waves wr=0 run the 4-step LIF.
// Grid: (N/64, BN/32), block 256.
// ---------------------------------------------------------------------------
__global__ __launch_bounds__(256) void gemm_lif(
    const void* __restrict__ A1v,
    const unsigned short* __restrict__ A2,     // nullable bf16 spike-sum
    const float* __restrict__ W,
    const float* __restrict__ bias,
    const unsigned short* Sprev,               // mode 1 (may alias outv)
    const float* __restrict__ Xres,            // mode 2
    const unsigned short* __restrict__ S12,    // mode 2
    void* outv,
    int N, int K, int mode, int a1bf) {
  // LDS (33.3 KB): As[r<128][k<16] pad 17 ; Bs[k<16][c<64] pad 66 at 2176 ;
  // epilogue overlays ship[i<32][p<128] pad 130 over the same space.
  __shared__ double smem[4160];
#define AS(r, k) smem[(size_t)(r) * 17 + (k)]
#define BS(k, c) smem[2176 + (size_t)(k) * 66 + (c)]
#define SHIP(i, p) smem[(size_t)(i) * 130 + (p)]

  const int tid = threadIdx.x;
  const int lane = tid & 63;
  const int wave = tid >> 6;
  const int wr = wave >> 1, wc = wave & 1;
  const int lm = lane & 15;        // A-row / B-col / C-col index
  const int kl = lane >> 4;        // k-slice 0..3 within mfma
  const int n0 = blockIdx.x * 64;
  const int bn0 = blockIdx.y * 32;

  // A staging: tile-row r_s = tid>>1 (0..127), k-half kh = (tid&1)*8
  const int r_s = tid >> 1;
  const int kh = (tid & 1) * 8;
  const size_t arow = (size_t)((r_s >> 5) * BN + bn0 + (r_s & 31)) * K;
  // B staging: k-row kb = tid>>4 (0..15), col-quad nq = (tid&15)*4
  const int kb = tid >> 4;
  const int nq = (tid & 15) * 4;

  d4 acc[4][2];
#pragma unroll
  for (int mt = 0; mt < 4; ++mt)
#pragma unroll
    for (int nt = 0; nt < 2; ++nt) acc[mt][nt] = (d4){0.0, 0.0, 0.0, 0.0};

  for (int k0 = 0; k0 < K; k0 += 16) {
    // ---- stage A (8 doubles, one row, consecutive k; exact spike add) ----
    {
      double ad[8];
      if (a1bf) {
        const unsigned short* A1 = (const unsigned short*)A1v;
        ushort4 p0 = *reinterpret_cast<const ushort4*>(A1 + arow + k0 + kh);
        ushort4 p1 = *reinterpret_cast<const ushort4*>(A1 + arow + k0 + kh + 4);
        ad[0] = (double)bf2f(p0.x); ad[1] = (double)bf2f(p0.y);
        ad[2] = (double)bf2f(p0.z); ad[3] = (double)bf2f(p0.w);
        ad[4] = (double)bf2f(p1.x); ad[5] = (double)bf2f(p1.y);
        ad[6] = (double)bf2f(p1.z); ad[7] = (double)bf2f(p1.w);
      } else {
        const float* A1 = (const float*)A1v;
        float4 p0 = *reinterpret_cast<const float4*>(A1 + arow + k0 + kh);
        float4 p1 = *reinterpret_cast<const float4*>(A1 + arow + k0 + kh + 4);
        ad[0] = (double)p0.x; ad[1] = (double)p0.y;
        ad[2] = (double)p0.z; ad[3] = (double)p0.w;
        ad[4] = (double)p1.x; ad[5] = (double)p1.y;
        ad[6] = (double)p1.z; ad[7] = (double)p1.w;
      }
      if (A2 != nullptr) {
        ushort4 q0 = *reinterpret_cast<const ushort4*>(A2 + arow + k0 + kh);
        ushort4 q1 = *reinterpret_cast<const ushort4*>(A2 + arow + k0 + kh + 4);
        ad[0] += (double)bf2f(q0.x); ad[1] += (double)bf2f(q0.y);
        ad[2] += (double)bf2f(q0.z); ad[3] += (double)bf2f(q0.w);
        ad[4] += (double)bf2f(q1.x); ad[5] += (double)bf2f(q1.y);
        ad[6] += (double)bf2f(q1.z); ad[7] += (double)bf2f(q1.w);
      }
#pragma unroll
      for (int j = 0; j < 8; ++j) AS(r_s, kh + j) = ad[j];
    }
    // ---- stage B (4 doubles, one k-row, consecutive cols) ----
    {
      float4 w4 = *reinterpret_cast<const float4*>(
          W + (size_t)(k0 + kb) * N + n0 + nq);
      BS(kb, nq + 0) = (double)w4.x;
      BS(kb, nq + 1) = (double)w4.y;
      BS(kb, nq + 2) = (double)w4.z;
      BS(kb, nq + 3) = (double)w4.w;
    }
    __syncthreads();
#pragma unroll
    for (int kc = 0; kc < 4; ++kc) {
      const int kk = kc * 4 + kl;
      double a0 = AS(wr * 64 + 0 * 16 + lm, kk);
      double a1 = AS(wr * 64 + 1 * 16 + lm, kk);
      double a2 = AS(wr * 64 + 2 * 16 + lm, kk);
      double a3 = AS(wr * 64 + 3 * 16 + lm, kk);
      double b0 = BS(kk, wc * 32 + lm);
      double b1 = BS(kk, wc * 32 + 16 + lm);
      acc[0][0] = __builtin_amdgcn_mfma_f64_16x16x4f64(a0, b0, acc[0][0], 0, 0, 0);
      acc[0][1] = __builtin_amdgcn_mfma_f64_16x16x4f64(a0, b1, acc[0][1], 0, 0, 0);
      acc[1][0] = __builtin_amdgcn_mfma_f64_16x16x4f64(a1, b0, acc[1][0], 0, 0, 0);
      acc[1][1] = __builtin_amdgcn_mfma_f64_16x16x4f64(a1, b1, acc[1][1], 0, 0, 0);
      acc[2][0] = __builtin_amdgcn_mfma_f64_16x16x4f64(a2, b0, acc[2][0], 0, 0, 0);
      acc[2][1] = __builtin_amdgcn_mfma_f64_16x16x4f64(a2, b1, acc[2][1], 0, 0, 0);
      acc[3][0] = __builtin_amdgcn_mfma_f64_16x16x4f64(a3, b0, acc[3][0], 0, 0, 0);
      acc[3][1] = __builtin_amdgcn_mfma_f64_16x16x4f64(a3, b1, acc[3][1], 0, 0, 0);
    }
    __syncthreads();
  }

  // ---- epilogue: waves wr=1 (t=2,3) ship accs via LDS; wr=0 runs LIF ----
  if (wr == 1) {
#pragma unroll
    for (int mt = 0; mt < 4; ++mt)
#pragma unroll
      for (int nt = 0; nt < 2; ++nt)
#pragma unroll
        for (int j = 0; j < 4; ++j)
          SHIP(mt * 8 + nt * 4 + j, wc * 64 + lane) = acc[mt][nt][j];
  }
  __syncthreads();
  if (wr == 0) {
#pragma unroll
    for (int nt = 0; nt < 2; ++nt) {
      const int col = n0 + wc * 32 + nt * 16 + lm;
      const double bb = (double)bias[col];
#pragma unroll
      for (int g = 0; g < 2; ++g) {
#pragma unroll
        for (int j = 0; j < 4; ++j) {
          const int bn = bn0 + g * 16 + kl * 4 + j;
          double u[4];
          u[0] = acc[g][nt][j] + bb;                              // t=0
          u[1] = acc[2 + g][nt][j] + bb;                          // t=1
          u[2] = SHIP(g * 8 + nt * 4 + j, wc * 64 + lane) + bb;   // t=2
          u[3] = SHIP((2 + g) * 8 + nt * 4 + j, wc * 64 + lane) + bb;  // t=3
          double v = 0.0;
#pragma unroll
          for (int t = 0; t < T_STEPS; ++t) {
            v = v + (u[t] - v) * 0.5;
            float s = (v >= 1.0) ? 1.0f : 0.0f;
            v = (v >= 1.0) ? 0.0 : v;
            size_t idx = (size_t)(t * BN + bn) * N + col;
            if (mode == MODE_SPK) {
              ((unsigned short*)outv)[idx] = f2bf(s);
            } else if (mode == MODE_SPK_ADD) {
              ((unsigned short*)outv)[idx] = f2bf(s + bf2f(Sprev[idx]));
            } else {
              ((float*)outv)[idx] =
                  (float)((double)Xres[idx] + (double)bf2f(S12[idx]) + (double)s);
            }
          }
        }
      }
    }
  }
#undef AS
#undef BS
#undef SHIP
}

// ---------------------------------------------------------------------------
// Spiking attention, reassociated: u = 0.125 * q @ (k^T @ v) per (t,b,h).
// Spikes are 0/1 -> exact integer sums (< 2^24) in f32; identical to the
// reference's (q@k^T)@v order. bf16 spikes in, exact f32 u out. Grid 128.
// ---------------------------------------------------------------------------
__global__ __launch_bounds__(256) void attn_k(const unsigned short* __restrict__ Q,
                                              const unsigned short* __restrict__ K,
                                              const unsigned short* __restrict__ V,
                                              float* __restrict__ O) {
  const int blk = blockIdx.x;
  const int h = blk & 7;
  const int tb = blk >> 3;
  const size_t base = (size_t)tb * (N_TOK * D_DIM) + h * 64;
  const int tid = threadIdx.x;
  const int tx = tid & 15, ty = tid >> 4;

  __shared__ float Kt[64][65];
  __shared__ float Vt[64][65];
  __shared__ float St[64][65];

  float S[4][4] = {};
  for (int mc = 0; mc < N_TOK; mc += 64) {
#pragma unroll
    for (int rr = 0; rr < 4; ++rr) {
      int row = rr * 16 + ty;
      ushort4 k4 = *reinterpret_cast<const ushort4*>(K + base + (size_t)(mc + row) * D_DIM + tx * 4);
      ushort4 v4 = *reinterpret_cast<const ushort4*>(V + base + (size_t)(mc + row) * D_DIM + tx * 4);
      Kt[row][tx * 4 + 0] = bf2f(k4.x); Kt[row][tx * 4 + 1] = bf2f(k4.y);
      Kt[row][tx * 4 + 2] = bf2f(k4.z); Kt[row][tx * 4 + 3] = bf2f(k4.w);
      Vt[row][tx * 4 + 0] = bf2f(v4.x); Vt[row][tx * 4 + 1] = bf2f(v4.y);
      Vt[row][tx * 4 + 2] = bf2f(v4.z); Vt[row][tx * 4 + 3] = bf2f(v4.w);
    }
    __syncthreads();
#pragma unroll 8
    for (int m = 0; m < 64; ++m) {
      float k0 = Kt[m][ty * 4 + 0], k1 = Kt[m][ty * 4 + 1];
      float k2 = Kt[m][ty * 4 + 2], k3 = Kt[m][ty * 4 + 3];
      float v0 = Vt[m][tx * 4 + 0], v1 = Vt[m][tx * 4 + 1];
      float v2 = Vt[m][tx * 4 + 2], v3 = Vt[m][tx * 4 + 3];
      S[0][0] += k0 * v0; S[0][1] += k0 * v1; S[0][2] += k0 * v2; S[0][3] += k0 * v3;
      S[1][0] += k1 * v0; S[1][1] += k1 * v1; S[1][2] += k1 * v2; S[1][3] += k1 * v3;
      S[2][0] += k2 * v0; S[2][1] += k2 * v1; S[2][2] += k2 * v2; S[2][3] += k2 * v3;
      S[3][0] += k3 * v0; S[3][1] += k3 * v1; S[3][2] += k3 * v2; S[3][3] += k3 * v3;
    }
    __syncthreads();
  }
#pragma unroll
  for (int i = 0; i < 4; ++i)
#pragma unroll
    for (int j = 0; j < 4; ++j) St[ty * 4 + i][tx * 4 + j] = S[i][j];
  __syncthreads();

  for (int nb = 0; nb < 8; ++nb) {
#pragma unroll
    for (int rr = 0; rr < 4; ++rr) {
      int row = rr * 16 + ty;
      ushort4 q4 = *reinterpret_cast<const ushort4*>(Q + base + (size_t)(nb * 64 + row) * D_DIM + tx * 4);
      Kt[row][tx * 4 + 0] = bf2f(q4.x); Kt[row][tx * 4 + 1] = bf2f(q4.y);
      Kt[row][tx * 4 + 2] = bf2f(q4.z); Kt[row][tx * 4 + 3] = bf2f(q4.w);
    }
    __syncthreads();
    float o[4][4] = {};
#pragma unroll 16
    for (int i = 0; i < 64; ++i) {
      float q0 = Kt[ty * 4 + 0][i], q1 = Kt[ty * 4 + 1][i];
      float q2 = Kt[ty * 4 + 2][i], q3 = Kt[ty * 4 + 3][i];
      float s0 = St[i][tx * 4 + 0], s1 = St[i][tx * 4 + 1];
      float s2 = St[i][tx * 4 + 2], s3 = St[i][tx * 4 + 3];
      o[0][0] += q0 * s0; o[0][1] += q0 * s1; o[0][2] += q0 * s2; o[0][3] += q0 * s3;
      o[1][0] += q1 * s0; o[1][1] += q1 * s1; o[1][2] += q1 * s2; o[1][3] += q1 * s3;
      o[2][0] += q2 * s0; o[2][1] += q2 * s1; o[2][2] += q2 * s2; o[2][3] += q2 * s3;
      o[3][0] += q3 * s0; o[3][1] += q3 * s1; o[3][2] += q3 * s2; o[3][3] += q3 * s3;
    }
#pragma unroll
    for (int r = 0; r < 4; ++r) {
      float4 ov;
      ov.x = o[r][0] * 0.125f; ov.y = o[r][1] * 0.125f;
      ov.z = o[r][2] * 0.125f; ov.w = o[r][3] * 0.125f;
      *reinterpret_cast<float4*>(O + base + (size_t)(nb * 64 + ty * 4 + r) * D_DIM + tx * 4) = ov;
    }
    __syncthreads();
  }
}

// ---------------------------------------------------------------------------
// LIF over attention u (exact f32 values, f64 state), writes bf16 spikes.
// ---------------------------------------------------------------------------
__global__ __launch_bounds__(256) void lif_plane(const float* __restrict__ U,
                                                 unsigned short* __restrict__ S) {
  int e = blockIdx.x * 256 + threadIdx.x;
  double v = 0.0;
#pragma unroll
  for (int t = 0; t < T_STEPS; ++t) {
    size_t idx = (size_t)t * (BN * D_DIM) + e;
    double u = (double)U[idx];
    v = v + (u - v) * 0.5;
    float s = (v >= 1.0) ? 1.0f : 0.0f;
    v = (v >= 1.0) ? 0.0 : v;
    S[idx] = f2bf(s);
  }
}

// ---------------------------------------------------------------------------
extern "C" void kernel_launch(void* const* d_in, const int* in_sizes, int n_in,
                              void* d_out, int out_size, void* d_ws, size_t ws_size,
                              hipStream_t stream) {
  const float* x    = (const float*)d_in[0];
  const float* enc  = (const float*)d_in[1];
  const float* Wq_s = (const float*)d_in[2];
  const float* bq_s = (const float*)d_in[3];
  const float* Wk_s = (const float*)d_in[4];
  const float* bk_s = (const float*)d_in[5];
  const float* Wv_s = (const float*)d_in[6];
  const float* bv_s = (const float*)d_in[7];
  const float* Wo_s = (const float*)d_in[8];
  const float* bo_s = (const float*)d_in[9];
  const float* Wq_c = (const float*)d_in[10];
  const float* bq_c = (const float*)d_in[11];
  const float* Wk_c = (const float*)d_in[12];
  const float* bk_c = (const float*)d_in[13];
  const float* Wv_c = (const float*)d_in[14];
  const float* bv_c = (const float*)d_in[15];
  const float* Wo_c = (const float*)d_in[16];
  const float* bo_c = (const float*)d_in[17];
  const float* W1   = (const float*)d_in[18];
  const float* b1   = (const float*)d_in[19];
  const float* W2   = (const float*)d_in[20];
  const float* b2   = (const float*)d_in[21];
  float* out = (float*)d_out;

  // Workspace (48 MB):
  //  0- 8 MB: qs (bf16 [R,D]); later attention spikes as_
  //  8-16 MB: ks;  8-40 MB later h_spk (bf16 [R,F], over ks/vs/u_attn)
  // 16-24 MB: vs
  // 24-40 MB: u_attn (f32 [R,D])
  // 40-48 MB: s1 (bf16 [R,D]) spike-sum of the two attention blocks
  char* pool = (char*)d_ws;
  const size_t MB = 1024 * 1024;
  unsigned short* qs     = (unsigned short*)(pool + 0 * MB);
  unsigned short* ks     = (unsigned short*)(pool + 8 * MB);
  unsigned short* vs     = (unsigned short*)(pool + 16 * MB);
  float*          u_attn = (float*)(pool + 24 * MB);
  unsigned short* as_    = (unsigned short*)(pool + 0 * MB);
  unsigned short* h_spk  = (unsigned short*)(pool + 8 * MB);
  unsigned short* s1     = (unsigned short*)(pool + 40 * MB);

  const unsigned short* NULS = nullptr;
  const float* NULF = nullptr;
  dim3 blk(256);
  dim3 gD(D_DIM / 64, BN / 32);   // (8, 64)
  dim3 gF(F_DIM / 64, BN / 32);   // (32, 64)
  int gLif = (BN * D_DIM) / 256;

  // ---- Block 1: self-attention ----
  gemm_lif<<<gD, blk, 0, stream>>>(x, NULS, Wq_s, bq_s, NULS, NULF, NULS, qs, D_DIM, D_DIM, MODE_SPK, 0);
  gemm_lif<<<gD, blk, 0, stream>>>(x, NULS, Wk_s, bk_s, NULS, NULF, NULS, ks, D_DIM, D_DIM, MODE_SPK, 0);
  gemm_lif<<<gD, blk, 0, stream>>>(x, NULS, Wv_s, bv_s, NULS, NULF, NULS, vs, D_DIM, D_DIM, MODE_SPK, 0);
  attn_k<<<128, blk, 0, stream>>>(qs, ks, vs, u_attn);
  lif_plane<<<gLif, blk, 0, stream>>>(u_attn, as_);
  gemm_lif<<<gD, blk, 0, stream>>>(as_, NULS, Wo_s, bo_s, NULS, NULF, NULS, s1, D_DIM, D_DIM, MODE_SPK, 1);

  // ---- Block 2: cross-attention (A_q = x + s1, exact via dual staging) ----
  gemm_lif<<<gD, blk, 0, stream>>>(x, s1, Wq_c, bq_c, NULS, NULF, NULS, qs, D_DIM, D_DIM, MODE_SPK, 0);
  gemm_lif<<<gD, blk, 0, stream>>>(enc, NULS, Wk_c, bk_c, NULS, NULF, NULS, ks, D_DIM, D_DIM, MODE_SPK, 0);
  gemm_lif<<<gD, blk, 0, stream>>>(enc, NULS, Wv_c, bv_c, NULS, NULF, NULS, vs, D_DIM, D_DIM, MODE_SPK, 0);
  attn_k<<<128, blk, 0, stream>>>(qs, ks, vs, u_attn);
  lif_plane<<<gLif, blk, 0, stream>>>(u_attn, as_);
  gemm_lif<<<gD, blk, 0, stream>>>(as_, NULS, Wo_c, bo_c, s1, NULF, NULS, s1, D_DIM, D_DIM, MODE_SPK_ADD, 1);

  // ---- Block 3: spiking MLP (A = x + s1; final fused residual output) ----
  gemm_lif<<<gF, blk, 0, stream>>>(x, s1, W1, b1, NULS, NULF, NULS, h_spk, F_DIM, D_DIM, MODE_SPK, 0);
  gemm_lif<<<gD, blk, 0, stream>>>(h_spk, NULS, W2, b2, NULS, x, s1, out, D_DIM, F_DIM, MODE_OUT, 1);

  (void)in_sizes; (void)n_in; (void)out_size; (void)ws_size;
}

// Round 6
// 1572.967 us; speedup vs baseline: 1.1112x; 1.1112x over previous
//
#include <hip/hip_runtime.h>
#include <cstddef>

// DecoderLayer: T=4, B=4, N=512, D=512, F=2048, H=8, head_dim=64
// I/O: float32. Spike intermediates: bf16 (exact for {0,1,2}).
// f64 MFMA GEMMs (absmax 0.0 proven rounds 3-5).
// Round 6: revert to round-4 64x64 tile (best: 388us FC, 59% MfmaUtil),
// add (1) register prefetch of next k-tile's global loads (hides HBM/L2
// latency outside the barrier drain), (2) B stored f32 in LDS (exact cvt
// on read; LDS 17.4->16.0 KB), (3) fused same-A multi-output dispatches
// (self QKV in one launch, cross K/V in one).
#define T_STEPS 4
#define BN 2048                    /* B*N rows per time plane */
#define N_TOK 512
#define D_DIM 512
#define F_DIM 2048

#define MODE_SPK 0
#define MODE_SPK_ADD 1
#define MODE_OUT 2

typedef double d4 __attribute__((ext_vector_type(4)));

__device__ __forceinline__ float bf2f(unsigned short u) {
  unsigned int x = ((unsigned int)u) << 16;
  float f;
  __builtin_memcpy(&f, &x, 4);
  return f;
}
__device__ __forceinline__ unsigned short f2bf(float f) {
  unsigned int x;
  __builtin_memcpy(&x, &f, 4);
  x += 0x7fffu + ((x >> 16) & 1u);  // round to nearest even
  return (unsigned short)(x >> 16);
}

// ---------------------------------------------------------------------------
// MFMA-f64 fused GEMM + LIF over T (round-4 verified structure + prefetch).
// Block tile: 64 cols x 64 rows, tile-row r = t*16 + bn_local.
// 4 waves: wr=w>>1 (row half), wc=w&1 (col half); wave tile 32x32 = 2x2
// 16x16 mfma tiles; m-tile mt covers t = wr*2 + mt.
// C/D 16x16 layout: col=lane&15, row=(lane>>4)*4+j (verified, absmax 0.0).
// Multi-output: blockIdx.x selects (W,bias,out) triple sel = blockIdx.x/nxb,
// so same-A GEMMs (QKV / KV) run in one dispatch.
// Grid: (nxb * ngemm, BN/16), block 256.
// ---------------------------------------------------------------------------
__global__ __launch_bounds__(256) void gemm_lif(
    const void* __restrict__ A1v,
    const unsigned short* __restrict__ A2,     // nullable bf16 spike-sum
    const float* __restrict__ Wa, const float* __restrict__ Wb,
    const float* __restrict__ Wc,
    const float* __restrict__ ba, const float* __restrict__ bb,
    const float* __restrict__ bc,
    const unsigned short* Sprev,               // mode 1 (may alias out)
    const float* __restrict__ Xres,            // mode 2
    const unsigned short* __restrict__ S12,    // mode 2
    void* outa, void* outb, void* outc,
    int N, int K, int nxb, int mode, int a1bf) {
  // LDS 16 KB: A f64 [k<16][r<64] stride 67 at smem[0..1072);
  // B f32 [k<16][c<64] stride 72 at bytes 8576.. (1152 floats);
  // epilogue overlay UX[i<16][p<128] covers all 2048 doubles.
  __shared__ double smem[2048];
  float* bsf = (float*)(smem + 1072);
#define AS(k, r) smem[(size_t)(k) * 67 + (r)]
#define BSF(k, c) bsf[(size_t)(k) * 72 + (c)]
#define UX(i, p) smem[(size_t)(i) * 128 + (p)]

  const int sel = (int)blockIdx.x / nxb;       // 0..2
  const int nb = (int)blockIdx.x - sel * nxb;
  const float* W = (sel == 0) ? Wa : ((sel == 1) ? Wb : Wc);
  const float* bias = (sel == 0) ? ba : ((sel == 1) ? bb : bc);
  void* outv = (sel == 0) ? outa : ((sel == 1) ? outb : outc);

  const int tid = threadIdx.x;
  const int lane = tid & 63;
  const int wave = tid >> 6;
  const int wr = wave >> 1, wc = wave & 1;
  const int lm = lane & 15;        // A-row / B-col / C-col index
  const int kl = lane >> 4;        // k-slice 0..3 within mfma
  const int n0 = nb * 64;
  const int bn0 = blockIdx.y * 16;

  // A staging: tile-row r_s = tid>>2 (0..63), k-quad kq_s = (tid&3)*4
  const int r_s = tid >> 2;
  const int kq_s = (tid & 3) * 4;
  const size_t arow = (size_t)((r_s >> 4) * BN + bn0 + (r_s & 15)) * K;
  // B staging: k-row kb = tid>>4 (0..15), col-quad nq = (tid&15)*4
  const int kb = tid >> 4;
  const int nq = (tid & 15) * 4;

  d4 acc00 = {0.0, 0.0, 0.0, 0.0};
  d4 acc01 = {0.0, 0.0, 0.0, 0.0};
  d4 acc10 = {0.0, 0.0, 0.0, 0.0};
  d4 acc11 = {0.0, 0.0, 0.0, 0.0};

  // prefetch registers
  float4 aF = {0.f, 0.f, 0.f, 0.f};
  ushort4 aU = {0, 0, 0, 0};
  ushort4 s4 = {0, 0, 0, 0};
  float4 wv;

#define LOAD_TILE(K0)                                                       \
  do {                                                                      \
    if (a1bf)                                                               \
      aU = *reinterpret_cast<const ushort4*>(                               \
          (const unsigned short*)A1v + arow + (K0) + kq_s);                 \
    else                                                                    \
      aF = *reinterpret_cast<const float4*>(                                \
          (const float*)A1v + arow + (K0) + kq_s);                          \
    if (A2 != nullptr)                                                      \
      s4 = *reinterpret_cast<const ushort4*>(A2 + arow + (K0) + kq_s);      \
    wv = *reinterpret_cast<const float4*>(W + (size_t)((K0) + kb) * N +     \
                                          n0 + nq);                         \
  } while (0)

  LOAD_TILE(0);

  for (int k0 = 0; k0 < K; k0 += 16) {
    // ---- stage current prefetched tile to LDS ----
    {
      double ad[4];
      if (a1bf) {
        ad[0] = (double)bf2f(aU.x); ad[1] = (double)bf2f(aU.y);
        ad[2] = (double)bf2f(aU.z); ad[3] = (double)bf2f(aU.w);
      } else {
        ad[0] = (double)aF.x; ad[1] = (double)aF.y;
        ad[2] = (double)aF.z; ad[3] = (double)aF.w;
      }
      if (A2 != nullptr) {
        ad[0] += (double)bf2f(s4.x); ad[1] += (double)bf2f(s4.y);
        ad[2] += (double)bf2f(s4.z); ad[3] += (double)bf2f(s4.w);
      }
      AS(kq_s + 0, r_s) = ad[0];
      AS(kq_s + 1, r_s) = ad[1];
      AS(kq_s + 2, r_s) = ad[2];
      AS(kq_s + 3, r_s) = ad[3];
      BSF(kb, nq + 0) = wv.x;
      BSF(kb, nq + 1) = wv.y;
      BSF(kb, nq + 2) = wv.z;
      BSF(kb, nq + 3) = wv.w;
    }
    __syncthreads();
    // ---- issue next tile's global loads (latency hidden behind mfma) ----
    if (k0 + 16 < K) LOAD_TILE(k0 + 16);
    // ---- mfma from LDS ----
#pragma unroll
    for (int kc = 0; kc < 4; ++kc) {
      const int kk = kc * 4 + kl;
      double a0 = AS(kk, wr * 32 + lm);
      double a1 = AS(kk, wr * 32 + 16 + lm);
      double b0 = (double)BSF(kk, wc * 32 + lm);
      double b1 = (double)BSF(kk, wc * 32 + 16 + lm);
      acc00 = __builtin_amdgcn_mfma_f64_16x16x4f64(a0, b0, acc00, 0, 0, 0);
      acc01 = __builtin_amdgcn_mfma_f64_16x16x4f64(a0, b1, acc01, 0, 0, 0);
      acc10 = __builtin_amdgcn_mfma_f64_16x16x4f64(a1, b0, acc10, 0, 0, 0);
      acc11 = __builtin_amdgcn_mfma_f64_16x16x4f64(a1, b1, acc11, 0, 0, 0);
    }
    __syncthreads();
  }
#undef LOAD_TILE

  // ---- epilogue: waves wr=1 (t=2,3) ship accs via LDS; wr=0 runs LIF ----
  if (wr == 1) {
#pragma unroll
    for (int j = 0; j < 4; ++j) {
      UX(0 + 0 * 4 + j, wc * 64 + lane) = acc00[j];  // mt0 (t=2), nt0
      UX(0 + 1 * 4 + j, wc * 64 + lane) = acc01[j];  // mt0 (t=2), nt1
      UX(8 + 0 * 4 + j, wc * 64 + lane) = acc10[j];  // mt1 (t=3), nt0
      UX(8 + 1 * 4 + j, wc * 64 + lane) = acc11[j];  // mt1 (t=3), nt1
    }
  }
  __syncthreads();
  if (wr == 0) {
    const double bd[2] = {(double)bias[n0 + wc * 32 + lm],
                          (double)bias[n0 + wc * 32 + 16 + lm]};
#pragma unroll
    for (int nt = 0; nt < 2; ++nt) {
      const int col = n0 + wc * 32 + nt * 16 + lm;
      const double bb2 = bd[nt];
#pragma unroll
      for (int j = 0; j < 4; ++j) {
        const int bn = bn0 + kl * 4 + j;
        double u[4];
        u[0] = (nt ? acc01[j] : acc00[j]) + bb2;           // t=0
        u[1] = (nt ? acc11[j] : acc10[j]) + bb2;           // t=1
        u[2] = UX(0 + nt * 4 + j, wc * 64 + lane) + bb2;   // t=2
        u[3] = UX(8 + nt * 4 + j, wc * 64 + lane) + bb2;   // t=3
        double v = 0.0;
#pragma unroll
        for (int t = 0; t < T_STEPS; ++t) {
          v = v + (u[t] - v) * 0.5;
          float s = (v >= 1.0) ? 1.0f : 0.0f;
          v = (v >= 1.0) ? 0.0 : v;
          size_t idx = (size_t)(t * BN + bn) * N + col;
          if (mode == MODE_SPK) {
            ((unsigned short*)outv)[idx] = f2bf(s);
          } else if (mode == MODE_SPK_ADD) {
            ((unsigned short*)outv)[idx] = f2bf(s + bf2f(Sprev[idx]));
          } else {
            ((float*)outv)[idx] =
                (float)((double)Xres[idx] + (double)bf2f(S12[idx]) + (double)s);
          }
        }
      }
    }
  }
#undef AS
#undef BSF
#undef UX
}

// ---------------------------------------------------------------------------
// Spiking attention, reassociated: u = 0.125 * q @ (k^T @ v) per (t,b,h).
// Spikes are 0/1 -> exact integer sums (< 2^24) in f32; identical to the
// reference's (q@k^T)@v order. bf16 spikes in, exact f32 u out. Grid 128.
// ---------------------------------------------------------------------------
__global__ __launch_bounds__(256) void attn_k(const unsigned short* __restrict__ Q,
                                              const unsigned short* __restrict__ K,
                                              const unsigned short* __restrict__ V,
                                              float* __restrict__ O) {
  const int blk = blockIdx.x;
  const int h = blk & 7;
  const int tb = blk >> 3;
  const size_t base = (size_t)tb * (N_TOK * D_DIM) + h * 64;
  const int tid = threadIdx.x;
  const int tx = tid & 15, ty = tid >> 4;

  __shared__ float Kt[64][65];
  __shared__ float Vt[64][65];
  __shared__ float St[64][65];

  float S[4][4] = {};
  for (int mc = 0; mc < N_TOK; mc += 64) {
#pragma unroll
    for (int rr = 0; rr < 4; ++rr) {
      int row = rr * 16 + ty;
      ushort4 k4 = *reinterpret_cast<const ushort4*>(K + base + (size_t)(mc + row) * D_DIM + tx * 4);
      ushort4 v4 = *reinterpret_cast<const ushort4*>(V + base + (size_t)(mc + row) * D_DIM + tx * 4);
      Kt[row][tx * 4 + 0] = bf2f(k4.x); Kt[row][tx * 4 + 1] = bf2f(k4.y);
      Kt[row][tx * 4 + 2] = bf2f(k4.z); Kt[row][tx * 4 + 3] = bf2f(k4.w);
      Vt[row][tx * 4 + 0] = bf2f(v4.x); Vt[row][tx * 4 + 1] = bf2f(v4.y);
      Vt[row][tx * 4 + 2] = bf2f(v4.z); Vt[row][tx * 4 + 3] = bf2f(v4.w);
    }
    __syncthreads();
#pragma unroll 8
    for (int m = 0; m < 64; ++m) {
      float k0 = Kt[m][ty * 4 + 0], k1 = Kt[m][ty * 4 + 1];
      float k2 = Kt[m][ty * 4 + 2], k3 = Kt[m][ty * 4 + 3];
      float v0 = Vt[m][tx * 4 + 0], v1 = Vt[m][tx * 4 + 1];
      float v2 = Vt[m][tx * 4 + 2], v3 = Vt[m][tx * 4 + 3];
      S[0][0] += k0 * v0; S[0][1] += k0 * v1; S[0][2] += k0 * v2; S[0][3] += k0 * v3;
      S[1][0] += k1 * v0; S[1][1] += k1 * v1; S[1][2] += k1 * v2; S[1][3] += k1 * v3;
      S[2][0] += k2 * v0; S[2][1] += k2 * v1; S[2][2] += k2 * v2; S[2][3] += k2 * v3;
      S[3][0] += k3 * v0; S[3][1] += k3 * v1; S[3][2] += k3 * v2; S[3][3] += k3 * v3;
    }
    __syncthreads();
  }
#pragma unroll
  for (int i = 0; i < 4; ++i)
#pragma unroll
    for (int j = 0; j < 4; ++j) St[ty * 4 + i][tx * 4 + j] = S[i][j];
  __syncthreads();

  for (int nb = 0; nb < 8; ++nb) {
#pragma unroll
    for (int rr = 0; rr < 4; ++rr) {
      int row = rr * 16 + ty;
      ushort4 q4 = *reinterpret_cast<const ushort4*>(Q + base + (size_t)(nb * 64 + row) * D_DIM + tx * 4);
      Kt[row][tx * 4 + 0] = bf2f(q4.x); Kt[row][tx * 4 + 1] = bf2f(q4.y);
      Kt[row][tx * 4 + 2] = bf2f(q4.z); Kt[row][tx * 4 + 3] = bf2f(q4.w);
    }
    __syncthreads();
    float o[4][4] = {};
#pragma unroll 16
    for (int i = 0; i < 64; ++i) {
      float q0 = Kt[ty * 4 + 0][i], q1 = Kt[ty * 4 + 1][i];
      float q2 = Kt[ty * 4 + 2][i], q3 = Kt[ty * 4 + 3][i];
      float s0 = St[i][tx * 4 + 0], s1 = St[i][tx * 4 + 1];
      float s2 = St[i][tx * 4 + 2], s3 = St[i][tx * 4 + 3];
      o[0][0] += q0 * s0; o[0][1] += q0 * s1; o[0][2] += q0 * s2; o[0][3] += q0 * s3;
      o[1][0] += q1 * s0; o[1][1] += q1 * s1; o[1][2] += q1 * s2; o[1][3] += q1 * s3;
      o[2][0] += q2 * s0; o[2][1] += q2 * s1; o[2][2] += q2 * s2; o[2][3] += q2 * s3;
      o[3][0] += q3 * s0; o[3][1] += q3 * s1; o[3][2] += q3 * s2; o[3][3] += q3 * s3;
    }
#pragma unroll
    for (int r = 0; r < 4; ++r) {
      float4 ov;
      ov.x = o[r][0] * 0.125f; ov.y = o[r][1] * 0.125f;
      ov.z = o[r][2] * 0.125f; ov.w = o[r][3] * 0.125f;
      *reinterpret_cast<float4*>(O + base + (size_t)(nb * 64 + ty * 4 + r) * D_DIM + tx * 4) = ov;
    }
    __syncthreads();
  }
}

// ---------------------------------------------------------------------------
// LIF over attention u (exact f32 values, f64 state), writes bf16 spikes.
// ---------------------------------------------------------------------------
__global__ __launch_bounds__(256) void lif_plane(const float* __restrict__ U,
                                                 unsigned short* __restrict__ S) {
  int e = blockIdx.x * 256 + threadIdx.x;
  double v = 0.0;
#pragma unroll
  for (int t = 0; t < T_STEPS; ++t) {
    size_t idx = (size_t)t * (BN * D_DIM) + e;
    double u = (double)U[idx];
    v = v + (u - v) * 0.5;
    float s = (v >= 1.0) ? 1.0f : 0.0f;
    v = (v >= 1.0) ? 0.0 : v;
    S[idx] = f2bf(s);
  }
}

// ---------------------------------------------------------------------------
extern "C" void kernel_launch(void* const* d_in, const int* in_sizes, int n_in,
                              void* d_out, int out_size, void* d_ws, size_t ws_size,
                              hipStream_t stream) {
  const float* x    = (const float*)d_in[0];
  const float* enc  = (const float*)d_in[1];
  const float* Wq_s = (const float*)d_in[2];
  const float* bq_s = (const float*)d_in[3];
  const float* Wk_s = (const float*)d_in[4];
  const float* bk_s = (const float*)d_in[5];
  const float* Wv_s = (const float*)d_in[6];
  const float* bv_s = (const float*)d_in[7];
  const float* Wo_s = (const float*)d_in[8];
  const float* bo_s = (const float*)d_in[9];
  const float* Wq_c = (const float*)d_in[10];
  const float* bq_c = (const float*)d_in[11];
  const float* Wk_c = (const float*)d_in[12];
  const float* bk_c = (const float*)d_in[13];
  const float* Wv_c = (const float*)d_in[14];
  const float* bv_c = (const float*)d_in[15];
  const float* Wo_c = (const float*)d_in[16];
  const float* bo_c = (const float*)d_in[17];
  const float* W1   = (const float*)d_in[18];
  const float* b1   = (const float*)d_in[19];
  const float* W2   = (const float*)d_in[20];
  const float* b2   = (const float*)d_in[21];
  float* out = (float*)d_out;

  // Workspace (48 MB):
  //  0- 8 MB: qs (bf16 [R,D]); later attention spikes as_
  //  8-16 MB: ks;  8-40 MB later h_spk (bf16 [R,F], over ks/vs/u_attn)
  // 16-24 MB: vs
  // 24-40 MB: u_attn (f32 [R,D])
  // 40-48 MB: s1 (bf16 [R,D]) spike-sum of the two attention blocks
  char* pool = (char*)d_ws;
  const size_t MB = 1024 * 1024;
  unsigned short* qs     = (unsigned short*)(pool + 0 * MB);
  unsigned short* ks     = (unsigned short*)(pool + 8 * MB);
  unsigned short* vs     = (unsigned short*)(pool + 16 * MB);
  float*          u_attn = (float*)(pool + 24 * MB);
  unsigned short* as_    = (unsigned short*)(pool + 0 * MB);
  unsigned short* h_spk  = (unsigned short*)(pool + 8 * MB);
  unsigned short* s1     = (unsigned short*)(pool + 40 * MB);

  const unsigned short* NULS = nullptr;
  const float* NULF = nullptr;
  dim3 blk(256);
  int gLif = (BN * D_DIM) / 256;

  // ---- Block 1: self-attention (QKV fused: one dispatch, 3 outputs) ----
  gemm_lif<<<dim3(24, 128), blk, 0, stream>>>(
      x, NULS, Wq_s, Wk_s, Wv_s, bq_s, bk_s, bv_s,
      NULS, NULF, NULS, qs, ks, vs, D_DIM, D_DIM, 8, MODE_SPK, 0);
  attn_k<<<128, blk, 0, stream>>>(qs, ks, vs, u_attn);
  lif_plane<<<gLif, blk, 0, stream>>>(u_attn, as_);
  gemm_lif<<<dim3(8, 128), blk, 0, stream>>>(
      as_, NULS, Wo_s, Wo_s, Wo_s, bo_s, bo_s, bo_s,
      NULS, NULF, NULS, s1, s1, s1, D_DIM, D_DIM, 8, MODE_SPK, 1);

  // ---- Block 2: cross-attention (Q: A=x+s1; K/V fused over enc) ----
  gemm_lif<<<dim3(8, 128), blk, 0, stream>>>(
      x, s1, Wq_c, Wq_c, Wq_c, bq_c, bq_c, bq_c,
      NULS, NULF, NULS, qs, qs, qs, D_DIM, D_DIM, 8, MODE_SPK, 0);
  gemm_lif<<<dim3(16, 128), blk, 0, stream>>>(
      enc, NULS, Wk_c, Wv_c, Wv_c, bk_c, bv_c, bv_c,
      NULS, NULF, NULS, ks, vs, vs, D_DIM, D_DIM, 8, MODE_SPK, 0);
  attn_k<<<128, blk, 0, stream>>>(qs, ks, vs, u_attn);
  lif_plane<<<gLif, blk, 0, stream>>>(u_attn, as_);
  gemm_lif<<<dim3(8, 128), blk, 0, stream>>>(
      as_, NULS, Wo_c, Wo_c, Wo_c, bo_c, bo_c, bo_c,
      s1, NULF, NULS, s1, s1, s1, D_DIM, D_DIM, 8, MODE_SPK_ADD, 1);

  // ---- Block 3: spiking MLP (A = x + s1; final fused residual output) ----
  gemm_lif<<<dim3(32, 128), blk, 0, stream>>>(
      x, s1, W1, W1, W1, b1, b1, b1,
      NULS, NULF, NULS, h_spk, h_spk, h_spk, F_DIM, D_DIM, 32, MODE_SPK, 0);
  gemm_lif<<<dim3(8, 128), blk, 0, stream>>>(
      h_spk, NULS, W2, W2, W2, b2, b2, b2,
      NULS, x, s1, out, out, out, D_DIM, F_DIM, 8, MODE_OUT, 1);

  (void)in_sizes; (void)n_in; (void)out_size; (void)ws_size;
}